// Round 2
// baseline (331.307 us; speedup 1.0000x reference)
//
#include <hip/hip_runtime.h>

// MHA fwd: B=2, S=2048, d=1024, H=16, hd=64. fp32 accum, bf16 MFMA compute.
// Dtype-adaptive: a detect kernel decides whether d_in tensors are fp32 or bf16;
// inputs are converted to bf16 workspace buffers either way.

typedef __bf16 bf16;
typedef __bf16 bf16x8 __attribute__((ext_vector_type(8)));
typedef float f32x4 __attribute__((ext_vector_type(4)));

#define DEV static __device__ __forceinline__

constexpr int D = 1024;
constexpr int NH = 16;
constexpr int HD = 64;
constexpr int B_ = 2;
constexpr int S_ = 2048;
constexpr size_t MAT = (size_t)D * D;        // 1,048,576
constexpr size_t XSZ = (size_t)B_ * S_ * D;  // 4,194,304

// async global->LDS, 16B per lane, wave-uniform LDS base + lane*16 (m97 pattern)
DEV void glds16(const bf16* g, bf16* l) {
  __builtin_amdgcn_global_load_lds(
      (__attribute__((address_space(1))) void*)g,
      (__attribute__((address_space(3))) void*)l, 16, 0, 0);
}

// ---------------- dtype detection ----------------
// If the buffer holds fp32, the low u16 of each float has ~uniform exponent bits:
// ~44% of scanned u16s show biased exp >= 0x90 (|x| >= 2^17). bf16 N(0,1/32) data: none.
__global__ __launch_bounds__(256) void detect_k(const unsigned short* __restrict__ w,
                                                int* __restrict__ flag) {
  __shared__ int sbuf[256];
  const int tid = threadIdx.x;
  int cnt = 0;
  for (int i = tid; i < 8192; i += 256) {
    const unsigned e = (w[i] >> 7) & 0xFF;
    if (e >= 0x90) cnt++;
  }
  sbuf[tid] = cnt;
  __syncthreads();
  for (int s = 128; s > 0; s >>= 1) {
    if (tid < s) sbuf[tid] += sbuf[tid + s];
    __syncthreads();
  }
  if (tid == 0) flag[0] = (sbuf[0] > 32) ? 1 : 0;
}

// ---------------- input conversion ----------------
__global__ __launch_bounds__(256) void convert_x(const void* __restrict__ X0,
                                                 const void* __restrict__ X1,
                                                 const void* __restrict__ X2,
                                                 const int* __restrict__ flag,
                                                 bf16* __restrict__ Xc) {
  const int isf = *flag;
  const void* s = (blockIdx.y == 0) ? X0 : (blockIdx.y == 1) ? X1 : X2;
  const size_t base = ((size_t)blockIdx.x * 256 + threadIdx.x) * 8;
  bf16* dst = Xc + (size_t)blockIdx.y * XSZ + base;
  if (isf) {
    const float* f = (const float*)s + base;
#pragma unroll
    for (int j = 0; j < 8; j++) dst[j] = (bf16)f[j];
  } else {
    *(bf16x8*)dst = *(const bf16x8*)((const bf16*)s + base);
  }
}

__global__ __launch_bounds__(256) void convert_bias(const void* __restrict__ b0,
                                                    const void* __restrict__ b1,
                                                    const void* __restrict__ b2,
                                                    const void* __restrict__ b3,
                                                    const int* __restrict__ flag,
                                                    bf16* __restrict__ bc) {
  const int isf = *flag;
  const int m = blockIdx.x;
  const void* s = (m == 0) ? b0 : (m == 1) ? b1 : (m == 2) ? b2 : b3;
  bf16* dst = bc + m * 1024;
  for (int i = threadIdx.x; i < 1024; i += 256)
    dst[i] = isf ? (bf16)((const float*)s)[i] : ((const bf16*)s)[i];
}

// transpose 4 weight matrices [1024][1024] -> WT4 (row-major [out][in] each), flag-aware read
__global__ __launch_bounds__(256) void transpose4(const void* __restrict__ W0,
                                                  const void* __restrict__ W1,
                                                  const void* __restrict__ W2,
                                                  const void* __restrict__ W3,
                                                  const int* __restrict__ flag,
                                                  bf16* __restrict__ out) {
  __shared__ bf16 t[64][65];
  const int isf = *flag;
  const int mat = blockIdx.z;
  const void* W = (mat == 0) ? W0 : (mat == 1) ? W1 : (mat == 2) ? W2 : W3;
  bf16* o = out + (size_t)mat * MAT;
  const int r0 = blockIdx.y * 64, c0 = blockIdx.x * 64;
  const int tt = threadIdx.x;
#pragma unroll
  for (int e = 0; e < 16; e++) {
    const int idx = tt + e * 256;
    const size_t gi = (size_t)(r0 + (idx >> 6)) * D + c0 + (idx & 63);
    t[idx >> 6][idx & 63] = isf ? (bf16)((const float*)W)[gi] : ((const bf16*)W)[gi];
  }
  __syncthreads();
#pragma unroll
  for (int e = 0; e < 16; e++) {
    const int idx = tt + e * 256;
    const int co = idx >> 6, ro = idx & 63;
    o[(size_t)(c0 + co) * D + r0 + ro] = t[ro][co];
  }
}

// ---------------- GEMM core ----------------
// 128x128 C tile, 4 waves each 64x64 (4x4 mfma_16x16x32_bf16), BK=64.
// LDS layout: [row][8 chunks of 8 bf16], chunk XOR-swizzled by (row&7).
DEV void gemm_core(const bf16* __restrict__ A, const bf16* __restrict__ WT,
                   int m0, int n0, bf16* As, bf16* Bs, f32x4 acc[4][4]) {
  const int tid = threadIdx.x;
  const int w = tid >> 6, lane = tid & 63;
  const int ln = lane & 15, qd = lane >> 4;
  const int wr = w >> 1, wc = w & 1;
  const int l8r = lane >> 3, l8c = lane & 7;
  const int swz8 = ((l8c ^ l8r) * 8);

  // pre-zero LDS (diagnostic: any staging hole reads 0, not junk)
  const uint4 z4 = {0u, 0u, 0u, 0u};
  for (int idx = tid; idx < 1024; idx += 256) {
    ((uint4*)As)[idx] = z4;
    ((uint4*)Bs)[idx] = z4;
  }

#pragma unroll
  for (int i = 0; i < 4; i++)
#pragma unroll
    for (int j = 0; j < 4; j++) acc[i][j] = (f32x4){0.f, 0.f, 0.f, 0.f};

  for (int k0 = 0; k0 < D; k0 += 64) {
    __syncthreads();  // protect previous iter's LDS reads (and the zero-fill)
#pragma unroll
    for (int t = 0; t < 4; t++) {
      const int c = w * 4 + t;  // 16 chunks of 8 rows x 64 cols
      glds16(A + (size_t)(m0 + c * 8 + l8r) * D + k0 + swz8, As + c * 512);
      glds16(WT + (size_t)(n0 + c * 8 + l8r) * D + k0 + swz8, Bs + c * 512);
    }
    __syncthreads();  // drains vmcnt(0) -> glds data visible
#pragma unroll
    for (int ks = 0; ks < 2; ks++) {
      bf16x8 af[4], bfr[4];
#pragma unroll
      for (int i = 0; i < 4; i++)
        af[i] = *(const bf16x8*)(As + (wr * 64 + i * 16 + ln) * 64 +
                                 (((ks * 4 + qd) ^ (ln & 7)) * 8));
#pragma unroll
      for (int j = 0; j < 4; j++)
        bfr[j] = *(const bf16x8*)(Bs + (wc * 64 + j * 16 + ln) * 64 +
                                  (((ks * 4 + qd) ^ (ln & 7)) * 8));
#pragma unroll
      for (int i = 0; i < 4; i++)
#pragma unroll
        for (int j = 0; j < 4; j++)
          acc[i][j] = __builtin_amdgcn_mfma_f32_16x16x32_bf16(af[i], bfr[j], acc[i][j], 0, 0, 0);
    }
  }
}

// Fused Q/K/V projection. grid (32 m-tiles, 24 n-blocks): nb/8 selects matrix.
// Q,K stored [B,H,S,hd]; V stored transposed [B,H,hd,S].
__global__ __launch_bounds__(256) void qkv_kernel(
    const bf16* __restrict__ Xc, const bf16* __restrict__ WT4, const bf16* __restrict__ bc,
    bf16* __restrict__ Qb, bf16* __restrict__ Kb, bf16* __restrict__ VTb) {
  __shared__ __align__(16) bf16 As[128 * 64];
  __shared__ __align__(16) bf16 Bs[128 * 64];
  const int mt = blockIdx.x;
  const int nb = blockIdx.y;
  const int mat = nb >> 3;
  const int n0 = (nb & 7) * 128;
  const bf16* A = Xc + (size_t)mat * XSZ;
  const bf16* WT = WT4 + (size_t)mat * MAT;
  const bf16* bias = bc + mat * 1024;

  f32x4 acc[4][4];
  gemm_core(A, WT, mt * 128, n0, As, Bs, acc);

  const int tid = threadIdx.x;
  const int w = tid >> 6, lane = tid & 63;
  const int ln = lane & 15, qd = lane >> 4;
  const int wr = w >> 1, wc = w & 1;

#pragma unroll
  for (int i = 0; i < 4; i++)
#pragma unroll
    for (int j = 0; j < 4; j++) {
      const int col = n0 + wc * 64 + j * 16 + ln;
      const float bb = (float)bias[col];
      const int h = col >> 6, dd = col & 63;
#pragma unroll
      for (int r = 0; r < 4; r++) {
        const int tok = mt * 128 + wr * 64 + i * 16 + qd * 4 + r;
        const int b = tok >> 11, s = tok & (S_ - 1);
        const float v = acc[i][j][r] + bb;
        if (mat == 2) {
          VTb[(size_t)((b * NH + h) * HD + dd) * S_ + s] = (bf16)v;
        } else {
          bf16* dst = (mat == 0) ? Qb : Kb;
          dst[(size_t)((b * NH + h) * S_ + s) * HD + dd] = (bf16)v;
        }
      }
    }
}

// Flash attention. grid (16 q-tiles, 32 bh). 4 waves, each owns 32 q-rows.
__global__ __launch_bounds__(256) void attn_kernel(const bf16* __restrict__ Qb,
                                                   const bf16* __restrict__ Kb,
                                                   const bf16* __restrict__ VTb,
                                                   bf16* __restrict__ Ob) {
  __shared__ __align__(16) bf16 Ks[128 * 64];   // [key][dd], swizzled
  __shared__ __align__(16) bf16 Vs[64 * 128];   // [dd][key], swizzled
  __shared__ __align__(16) bf16 Ps[128 * 128];  // [q][key], swizzled, wave-private rows

  const int qt = blockIdx.x;
  const int bh = blockIdx.y;
  const int tid = threadIdx.x;
  const int w = tid >> 6, lane = tid & 63;
  const int ln = lane & 15, qd = lane >> 4;
  const int l8r = lane >> 3, l8c = lane & 7;
  const int l16r = lane >> 4, l16c = lane & 15;

  // pre-zero all LDS (diagnostic: junk can never feed MFMA)
  {
    const uint4 z4 = {0u, 0u, 0u, 0u};
    for (int idx = tid; idx < 1024; idx += 256) {
      ((uint4*)Ks)[idx] = z4;
      ((uint4*)Vs)[idx] = z4;
    }
    for (int idx = tid; idx < 2048; idx += 256) ((uint4*)Ps)[idx] = z4;
  }

  const size_t base = (size_t)bh * S_ * HD;
  const int q0 = qt * 128;

  // Q fragments held in registers for whole kernel (A-operand layout)
  bf16x8 qf[2][2];
#pragma unroll
  for (int i = 0; i < 2; i++)
#pragma unroll
    for (int t = 0; t < 2; t++)
      qf[i][t] = *(const bf16x8*)(Qb + base + (size_t)(q0 + w * 32 + i * 16 + ln) * HD +
                                  t * 32 + qd * 8);

  f32x4 acc_o[2][4];
#pragma unroll
  for (int i = 0; i < 2; i++)
#pragma unroll
    for (int j = 0; j < 4; j++) acc_o[i][j] = (f32x4){0.f, 0.f, 0.f, 0.f};
  float m_i[2][4], l_i[2][4];
#pragma unroll
  for (int i = 0; i < 2; i++)
#pragma unroll
    for (int r = 0; r < 4; r++) { m_i[i][r] = -1e30f; l_i[i][r] = 0.f; }

  for (int kt = 0; kt < S_ / 128; kt++) {
    const int k0 = kt * 128;
    __syncthreads();
#pragma unroll
    for (int t = 0; t < 4; t++) {
      const int c = w * 4 + t;
      glds16(Kb + base + (size_t)(k0 + c * 8 + l8r) * HD + ((l8c ^ l8r) * 8), Ks + c * 512);
      const int dd = c * 4 + l16r;
      glds16(VTb + base + (size_t)dd * S_ + k0 + ((l16c ^ (dd & 15)) * 8), Vs + c * 512);
    }
    __syncthreads();

    // S = Q K^T (per wave: 32 q x 128 k)
    f32x4 sacc[2][8];
#pragma unroll
    for (int i = 0; i < 2; i++)
#pragma unroll
      for (int j = 0; j < 8; j++) sacc[i][j] = (f32x4){0.f, 0.f, 0.f, 0.f};
#pragma unroll
    for (int t = 0; t < 2; t++) {
      bf16x8 kf[8];
#pragma unroll
      for (int j = 0; j < 8; j++)
        kf[j] = *(const bf16x8*)(Ks + (j * 16 + ln) * 64 + (((t * 4 + qd) ^ (ln & 7)) * 8));
#pragma unroll
      for (int i = 0; i < 2; i++)
#pragma unroll
        for (int j = 0; j < 8; j++)
          sacc[i][j] = __builtin_amdgcn_mfma_f32_16x16x32_bf16(qf[i][t], kf[j], sacc[i][j], 0, 0, 0);
    }

#pragma unroll
    for (int i = 0; i < 2; i++)
#pragma unroll
      for (int j = 0; j < 8; j++) sacc[i][j] *= 0.125f;  // 1/sqrt(64)

    // online softmax; row = qd*4+r (C layout), cols spread over ln (16 lanes) x 8 frags
#pragma unroll
    for (int i = 0; i < 2; i++) {
#pragma unroll
      for (int r = 0; r < 4; r++) {
        float mx = sacc[i][0][r];
#pragma unroll
        for (int j = 1; j < 8; j++) mx = fmaxf(mx, sacc[i][j][r]);
        mx = fmaxf(mx, __shfl_xor(mx, 1, 64));
        mx = fmaxf(mx, __shfl_xor(mx, 2, 64));
        mx = fmaxf(mx, __shfl_xor(mx, 4, 64));
        mx = fmaxf(mx, __shfl_xor(mx, 8, 64));
        const float mnew = fmaxf(m_i[i][r], mx);
        const float alpha = __expf(m_i[i][r] - mnew);
        m_i[i][r] = mnew;
        float rs = 0.f;
#pragma unroll
        for (int j = 0; j < 8; j++) {
          const float p = __expf(sacc[i][j][r] - mnew);
          sacc[i][j][r] = p;
          rs += p;
        }
        rs += __shfl_xor(rs, 1, 64);
        rs += __shfl_xor(rs, 2, 64);
        rs += __shfl_xor(rs, 4, 64);
        rs += __shfl_xor(rs, 8, 64);
        l_i[i][r] = l_i[i][r] * alpha + rs;
#pragma unroll
        for (int jn = 0; jn < 4; jn++) acc_o[i][jn][r] *= alpha;
      }
    }

    // P: C-layout regs -> LDS (bf16, swizzled) -> A-layout reads (wave-private rows)
#pragma unroll
    for (int i = 0; i < 2; i++)
#pragma unroll
      for (int j = 0; j < 8; j++) {
        const int colb = j * 16 + ln;
        const int lc = colb >> 3, cs = colb & 7;
#pragma unroll
        for (int r = 0; r < 4; r++) {
          const int qrow = w * 32 + i * 16 + qd * 4 + r;
          Ps[qrow * 128 + ((lc ^ (qrow & 15)) * 8) + cs] = (bf16)sacc[i][j][r];
        }
      }

    // O += P V  (k-dim = 128 keys = 4 mfma steps)
#pragma unroll
    for (int t = 0; t < 4; t++) {
      bf16x8 pf[2], vf[4];
#pragma unroll
      for (int i = 0; i < 2; i++) {
        const int m = w * 32 + i * 16 + ln;
        pf[i] = *(const bf16x8*)(Ps + m * 128 + (((t * 4 + qd) ^ (m & 15)) * 8));
      }
#pragma unroll
      for (int jn = 0; jn < 4; jn++)
        vf[jn] = *(const bf16x8*)(Vs + (jn * 16 + ln) * 128 + (((t * 4 + qd) ^ ln) * 8));
#pragma unroll
      for (int i = 0; i < 2; i++)
#pragma unroll
        for (int jn = 0; jn < 4; jn++)
          acc_o[i][jn] = __builtin_amdgcn_mfma_f32_16x16x32_bf16(pf[i], vf[jn], acc_o[i][jn], 0, 0, 0);
    }
  }

  // epilogue: O[token][h*64+dd], token-major for final GEMM
  const int b = bh >> 4, h = bh & 15;
#pragma unroll
  for (int i = 0; i < 2; i++)
#pragma unroll
    for (int jn = 0; jn < 4; jn++)
#pragma unroll
      for (int r = 0; r < 4; r++) {
        const int q = q0 + w * 32 + i * 16 + qd * 4 + r;
        const int dd = jn * 16 + ln;
        const float v = acc_o[i][jn][r] / l_i[i][r];
        Ob[(size_t)(b * S_ + q) * D + h * HD + dd] = (bf16)v;
      }
}

// final projection: out = O @ Wo + bo; output dtype per flag
__global__ __launch_bounds__(256) void oproj_kernel(const bf16* __restrict__ Ob,
                                                    const bf16* __restrict__ WoT,
                                                    const bf16* __restrict__ bo,
                                                    const int* __restrict__ flag,
                                                    void* __restrict__ outv) {
  __shared__ __align__(16) bf16 As[128 * 64];
  __shared__ __align__(16) bf16 Bs[128 * 64];
  const int isf = *flag;
  const int mt = blockIdx.x, nb = blockIdx.y;
  f32x4 acc[4][4];
  gemm_core(Ob, WoT, mt * 128, nb * 128, As, Bs, acc);
  const int tid = threadIdx.x;
  const int w = tid >> 6, lane = tid & 63;
  const int ln = lane & 15, qd = lane >> 4;
  const int wr = w >> 1, wc = w & 1;
#pragma unroll
  for (int i = 0; i < 4; i++)
#pragma unroll
    for (int j = 0; j < 4; j++) {
      const int col = nb * 128 + wc * 64 + j * 16 + ln;
      const float bb = (float)bo[col];
#pragma unroll
      for (int r = 0; r < 4; r++) {
        const int tok = mt * 128 + wr * 64 + i * 16 + qd * 4 + r;
        const float v = acc[i][j][r] + bb;
        const size_t oi = (size_t)tok * D + col;
        if (isf) ((float*)outv)[oi] = v;
        else ((bf16*)outv)[oi] = (bf16)v;
      }
    }
}

extern "C" void kernel_launch(void* const* d_in, const int* in_sizes, int n_in,
                              void* d_out, int out_size, void* d_ws, size_t ws_size,
                              hipStream_t stream) {
  int* flag = (int*)d_ws;
  bf16* ws = (bf16*)d_ws + 2048;  // 4 KB header for the flag

  bf16* WT4 = ws;                       // 4*MAT
  bf16* Xc  = WT4 + 4 * MAT;            // 3*XSZ
  bf16* bc  = Xc + 3 * XSZ;             // 4096
  bf16* Qb  = bc + 4096;                // XSZ each
  bf16* Kb  = Qb + XSZ;
  bf16* VTb = Kb + XSZ;
  bf16* Ob  = VTb + XSZ;

  detect_k<<<1, 256, 0, stream>>>((const unsigned short*)d_in[3], flag);
  convert_x<<<dim3(2048, 3), 256, 0, stream>>>(d_in[0], d_in[1], d_in[2], flag, Xc);
  convert_bias<<<4, 256, 0, stream>>>(d_in[4], d_in[6], d_in[8], d_in[10], flag, bc);
  transpose4<<<dim3(16, 16, 4), 256, 0, stream>>>(d_in[3], d_in[5], d_in[7], d_in[9], flag, WT4);
  qkv_kernel<<<dim3(32, 24), 256, 0, stream>>>(Xc, WT4, bc, Qb, Kb, VTb);
  attn_kernel<<<dim3(16, 32), 256, 0, stream>>>(Qb, Kb, VTb, Ob);
  oproj_kernel<<<dim3(32, 8), 256, 0, stream>>>(Ob, WT4 + 3 * MAT, bc + 3 * 1024, flag, d_out);
}

// Round 3
// 319.067 us; speedup vs baseline: 1.0384x; 1.0384x over previous
//
#include <hip/hip_runtime.h>

// MHA fwd: B=2, S=2048, d=1024, H=16, hd=64. fp32 accum, bf16 MFMA compute.
// Dtype-adaptive: detect kernel decides fp32 vs bf16 inputs; all converted to bf16 ws.

typedef __bf16 bf16;
typedef __bf16 bf16x4 __attribute__((ext_vector_type(4)));
typedef __bf16 bf16x8 __attribute__((ext_vector_type(8)));
typedef float f32x4 __attribute__((ext_vector_type(4)));

#define DEV static __device__ __forceinline__

constexpr int D = 1024;
constexpr int NH = 16;
constexpr int HD = 64;
constexpr int B_ = 2;
constexpr int S_ = 2048;
constexpr size_t MAT = (size_t)D * D;        // 1,048,576
constexpr size_t XSZ = (size_t)B_ * S_ * D;  // 4,194,304

DEV void glds16(const bf16* g, bf16* l) {
  __builtin_amdgcn_global_load_lds(
      (__attribute__((address_space(1))) void*)g,
      (__attribute__((address_space(3))) void*)l, 16, 0, 0);
}

// ---------------- dtype detection ----------------
__global__ __launch_bounds__(256) void detect_k(const unsigned short* __restrict__ w,
                                                int* __restrict__ flag) {
  __shared__ int sbuf[256];
  const int tid = threadIdx.x;
  int cnt = 0;
  for (int i = tid; i < 8192; i += 256) {
    const unsigned e = (w[i] >> 7) & 0xFF;
    if (e >= 0x90) cnt++;
  }
  sbuf[tid] = cnt;
  __syncthreads();
  for (int s = 128; s > 0; s >>= 1) {
    if (tid < s) sbuf[tid] += sbuf[tid + s];
    __syncthreads();
  }
  if (tid == 0) flag[0] = (sbuf[0] > 32) ? 1 : 0;
}

// ---------------- input conversion ----------------
__global__ __launch_bounds__(256) void convert_x(const void* __restrict__ X0,
                                                 const void* __restrict__ X1,
                                                 const void* __restrict__ X2,
                                                 const int* __restrict__ flag,
                                                 bf16* __restrict__ Xc) {
  const int isf = *flag;
  const void* s = (blockIdx.y == 0) ? X0 : (blockIdx.y == 1) ? X1 : X2;
  const size_t base = ((size_t)blockIdx.x * 256 + threadIdx.x) * 8;
  bf16* dst = Xc + (size_t)blockIdx.y * XSZ + base;
  if (isf) {
    const float* f = (const float*)s + base;
#pragma unroll
    for (int j = 0; j < 8; j++) dst[j] = (bf16)f[j];
  } else {
    *(bf16x8*)dst = *(const bf16x8*)((const bf16*)s + base);
  }
}

__global__ __launch_bounds__(256) void convert_bias(const void* __restrict__ b0,
                                                    const void* __restrict__ b1,
                                                    const void* __restrict__ b2,
                                                    const void* __restrict__ b3,
                                                    const int* __restrict__ flag,
                                                    bf16* __restrict__ bc) {
  const int isf = *flag;
  const int m = blockIdx.x;
  const void* s = (m == 0) ? b0 : (m == 1) ? b1 : (m == 2) ? b2 : b3;
  bf16* dst = bc + m * 1024;
  for (int i = threadIdx.x; i < 1024; i += 256)
    dst[i] = isf ? (bf16)((const float*)s)[i] : ((const bf16*)s)[i];
}

// transpose 4 weight matrices [1024][1024] -> WT4 ([out][in] each), flag-aware read
__global__ __launch_bounds__(256) void transpose4(const void* __restrict__ W0,
                                                  const void* __restrict__ W1,
                                                  const void* __restrict__ W2,
                                                  const void* __restrict__ W3,
                                                  const int* __restrict__ flag,
                                                  bf16* __restrict__ out) {
  __shared__ bf16 t[64][65];
  const int isf = *flag;
  const int mat = blockIdx.z;
  const void* W = (mat == 0) ? W0 : (mat == 1) ? W1 : (mat == 2) ? W2 : W3;
  bf16* o = out + (size_t)mat * MAT;
  const int r0 = blockIdx.y * 64, c0 = blockIdx.x * 64;
  const int tt = threadIdx.x;
#pragma unroll
  for (int e = 0; e < 16; e++) {
    const int idx = tt + e * 256;
    const size_t gi = (size_t)(r0 + (idx >> 6)) * D + c0 + (idx & 63);
    t[idx >> 6][idx & 63] = isf ? (bf16)((const float*)W)[gi] : ((const bf16*)W)[gi];
  }
  __syncthreads();
#pragma unroll
  for (int e = 0; e < 16; e++) {
    const int idx = tt + e * 256;
    const int co = idx >> 6, ro = idx & 63;
    o[(size_t)(c0 + co) * D + r0 + ro] = t[ro][co];
  }
}

// ---------------- GEMM core (m97 pattern) ----------------
DEV void gemm_core(const bf16* __restrict__ A, const bf16* __restrict__ WT,
                   int m0, int n0, bf16* As, bf16* Bs, f32x4 acc[4][4]) {
  const int tid = threadIdx.x;
  const int w = tid >> 6, lane = tid & 63;
  const int ln = lane & 15, qd = lane >> 4;
  const int wr = w >> 1, wc = w & 1;
  const int l8r = lane >> 3, l8c = lane & 7;
  const int swz8 = ((l8c ^ l8r) * 8);

  const uint4 z4 = {0u, 0u, 0u, 0u};
  for (int idx = tid; idx < 1024; idx += 256) {
    ((uint4*)As)[idx] = z4;
    ((uint4*)Bs)[idx] = z4;
  }

#pragma unroll
  for (int i = 0; i < 4; i++)
#pragma unroll
    for (int j = 0; j < 4; j++) acc[i][j] = (f32x4){0.f, 0.f, 0.f, 0.f};

  for (int k0 = 0; k0 < D; k0 += 64) {
    __syncthreads();
#pragma unroll
    for (int t = 0; t < 4; t++) {
      const int c = w * 4 + t;
      glds16(A + (size_t)(m0 + c * 8 + l8r) * D + k0 + swz8, As + c * 512);
      glds16(WT + (size_t)(n0 + c * 8 + l8r) * D + k0 + swz8, Bs + c * 512);
    }
    __syncthreads();
#pragma unroll
    for (int ks = 0; ks < 2; ks++) {
      bf16x8 af[4], bfr[4];
#pragma unroll
      for (int i = 0; i < 4; i++)
        af[i] = *(const bf16x8*)(As + (wr * 64 + i * 16 + ln) * 64 +
                                 (((ks * 4 + qd) ^ (ln & 7)) * 8));
#pragma unroll
      for (int j = 0; j < 4; j++)
        bfr[j] = *(const bf16x8*)(Bs + (wc * 64 + j * 16 + ln) * 64 +
                                  (((ks * 4 + qd) ^ (ln & 7)) * 8));
#pragma unroll
      for (int i = 0; i < 4; i++)
#pragma unroll
        for (int j = 0; j < 4; j++)
          acc[i][j] = __builtin_amdgcn_mfma_f32_16x16x32_bf16(af[i], bfr[j], acc[i][j], 0, 0, 0);
    }
  }
}

// Fused Q/K/V projection. Q is pre-scaled by 0.125 (=1/sqrt(hd), exact in bf16).
// All three outputs stored head-major [b,h,s,dd] with coalesced-ish 32B chunks.
__global__ __launch_bounds__(256) void qkv_kernel(
    const bf16* __restrict__ Xc, const bf16* __restrict__ WT4, const bf16* __restrict__ bc,
    bf16* __restrict__ Qb, bf16* __restrict__ Kb, bf16* __restrict__ Vb) {
  __shared__ __align__(16) bf16 As[128 * 64];
  __shared__ __align__(16) bf16 Bs[128 * 64];
  const int mt = blockIdx.x;
  const int nb = blockIdx.y;
  const int mat = nb >> 3;
  const int n0 = (nb & 7) * 128;
  const bf16* A = Xc + (size_t)mat * XSZ;
  const bf16* WT = WT4 + (size_t)mat * MAT;
  const bf16* bias = bc + mat * 1024;

  f32x4 acc[4][4];
  gemm_core(A, WT, mt * 128, n0, As, Bs, acc);

  const int tid = threadIdx.x;
  const int w = tid >> 6, lane = tid & 63;
  const int ln = lane & 15, qd = lane >> 4;
  const int wr = w >> 1, wc = w & 1;
  bf16* dst = (mat == 0) ? Qb : (mat == 1) ? Kb : Vb;
  const float scale = (mat == 0) ? 0.125f : 1.0f;

#pragma unroll
  for (int i = 0; i < 4; i++)
#pragma unroll
    for (int j = 0; j < 4; j++) {
      const int col = n0 + wc * 64 + j * 16 + ln;
      const float bb = (float)bias[col];
      const int h = col >> 6, dd = col & 63;
#pragma unroll
      for (int r = 0; r < 4; r++) {
        const int tok = mt * 128 + wr * 64 + i * 16 + qd * 4 + r;
        const int b = tok >> 11, s = tok & (S_ - 1);
        dst[(size_t)((b * NH + h) * S_ + s) * HD + dd] = (bf16)((acc[i][j][r] + bb) * scale);
      }
    }
}

// V [b,h,s,dd] -> VT [b,h,dd,s], LDS-tiled, coalesced both sides
__global__ __launch_bounds__(256) void transpose_v(const bf16* __restrict__ Vb,
                                                   bf16* __restrict__ VTb) {
  __shared__ bf16 t[64][72];
  const int s0 = blockIdx.x * 64;
  const size_t base = (size_t)blockIdx.y * S_ * HD;
  const int tid = threadIdx.x;
#pragma unroll
  for (int e = 0; e < 16; e++) {
    const int idx = tid + e * 256;
    t[idx >> 6][idx & 63] = Vb[base + (size_t)(s0 + (idx >> 6)) * HD + (idx & 63)];
  }
  __syncthreads();
#pragma unroll
  for (int e = 0; e < 16; e++) {
    const int idx = tid + e * 256;
    const int dd = idx >> 6, sc = idx & 63;
    VTb[base + (size_t)dd * S_ + s0 + sc] = t[sc][dd];
  }
}

// Flash attention v2: barrier-free K-loop, direct-global K/V fragments, S^T softmax.
// grid (16 q-tiles, 32 bh). 4 waves, each owns 32 q-rows (wave-private P rows).
__global__ __launch_bounds__(256) void attn_kernel(const bf16* __restrict__ Qb,
                                                   const bf16* __restrict__ Kb,
                                                   const bf16* __restrict__ VTb,
                                                   bf16* __restrict__ Ob) {
  __shared__ __align__(16) bf16 P2[128 * 128];  // [q][key], 16B-chunk XOR swizzle by q&15

  const int qt = blockIdx.x;
  const int bh = blockIdx.y;
  const int tid = threadIdx.x;
  const int w = tid >> 6, lane = tid & 63;
  const int ln = lane & 15, qd = lane >> 4;

  const size_t base = (size_t)bh * S_ * HD;
  const int q0 = qt * 128;
  const bf16* Kp = Kb + base;
  const bf16* Vp = VTb + base;
  bf16* Pw = P2 + (w * 32) * 128;  // wave-private 32 rows

  // Q fragments in registers (A-layout of Q == B-layout of Q^T: same lane data)
  bf16x8 qf[2][2];
#pragma unroll
  for (int i = 0; i < 2; i++)
#pragma unroll
    for (int t = 0; t < 2; t++)
      qf[i][t] = *(const bf16x8*)(Qb + base + (size_t)(q0 + w * 32 + i * 16 + ln) * HD +
                                  t * 32 + qd * 8);

  f32x4 acc_o[2][4];
#pragma unroll
  for (int i = 0; i < 2; i++)
#pragma unroll
    for (int j = 0; j < 4; j++) acc_o[i][j] = (f32x4){0.f, 0.f, 0.f, 0.f};
  float m_i[2] = {-1e30f, -1e30f}, l_i[2] = {0.f, 0.f};

  for (int kt = 0; kt < S_ / 128; kt++) {
    const int k0 = kt * 128;

    // S^T = K Q^T : rows=key (8 blocks), cols=q (2 blocks). Lane owns q = i*16+ln.
    f32x4 st[2][8];
#pragma unroll
    for (int i = 0; i < 2; i++)
#pragma unroll
      for (int j = 0; j < 8; j++) st[i][j] = (f32x4){0.f, 0.f, 0.f, 0.f};
#pragma unroll
    for (int t = 0; t < 2; t++) {
      bf16x8 kf[8];
#pragma unroll
      for (int j = 0; j < 8; j++)
        kf[j] = *(const bf16x8*)(Kp + (size_t)(k0 + j * 16 + ln) * HD + t * 32 + qd * 8);
#pragma unroll
      for (int i = 0; i < 2; i++)
#pragma unroll
        for (int j = 0; j < 8; j++)
          st[i][j] = __builtin_amdgcn_mfma_f32_16x16x32_bf16(kf[j], qf[i][t], st[i][j], 0, 0, 0);
    }

    // online softmax, per-lane column ownership (scores pre-scaled via Q)
#pragma unroll
    for (int i = 0; i < 2; i++) {
      float mx = -1e30f;
#pragma unroll
      for (int j = 0; j < 8; j++)
#pragma unroll
        for (int r = 0; r < 4; r++) mx = fmaxf(mx, st[i][j][r]);
      mx = fmaxf(mx, __shfl_xor(mx, 16));
      mx = fmaxf(mx, __shfl_xor(mx, 32));
      const float mnew = fmaxf(m_i[i], mx);
      const float alpha = __expf(m_i[i] - mnew);
      m_i[i] = mnew;
      float rs = 0.f;
#pragma unroll
      for (int j = 0; j < 8; j++)
#pragma unroll
        for (int r = 0; r < 4; r++) {
          const float p = __expf(st[i][j][r] - mnew);
          st[i][j][r] = p;
          rs += p;
        }
      rs += __shfl_xor(rs, 16);
      rs += __shfl_xor(rs, 32);
      l_i[i] = l_i[i] * alpha + rs;

      // write P rows: lane's 4 consecutive keys -> packed b64
      {
        bf16* pr = Pw + (i * 16 + ln) * 128;
#pragma unroll
        for (int j = 0; j < 8; j++) {
          bf16x4 pv;
#pragma unroll
          for (int r = 0; r < 4; r++) pv[r] = (bf16)st[i][j][r];
          *(bf16x4*)(pr + (((j * 2 + (qd >> 1)) ^ ln) * 8) + (qd & 1) * 4) = pv;
        }
      }

      // rescale O accumulator (C-layout rows q = i*16 + qd*4 + r)
#pragma unroll
      for (int r = 0; r < 4; r++) {
        const float ar = __shfl(alpha, qd * 4 + r);
#pragma unroll
        for (int jn = 0; jn < 4; jn++) acc_o[i][jn][r] *= ar;
      }
    }

    // O += P V : A = P from LDS (b128), B = V^T direct from global (dwordx4)
#pragma unroll
    for (int t = 0; t < 4; t++) {
      bf16x8 vf[4], pf[2];
#pragma unroll
      for (int jn = 0; jn < 4; jn++)
        vf[jn] = *(const bf16x8*)(Vp + (size_t)(jn * 16 + ln) * S_ + k0 + t * 32 + qd * 8);
#pragma unroll
      for (int i = 0; i < 2; i++)
        pf[i] = *(const bf16x8*)(Pw + (i * 16 + ln) * 128 + (((t * 4 + qd) ^ ln) * 8));
#pragma unroll
      for (int i = 0; i < 2; i++)
#pragma unroll
        for (int jn = 0; jn < 4; jn++)
          acc_o[i][jn] = __builtin_amdgcn_mfma_f32_16x16x32_bf16(pf[i], vf[jn], acc_o[i][jn], 0, 0, 0);
    }
  }

  // epilogue: O[token][h*64+dd]
  const int b = bh >> 4, h = bh & 15;
#pragma unroll
  for (int i = 0; i < 2; i++)
#pragma unroll
    for (int r = 0; r < 4; r++) {
      const float lr = __shfl(l_i[i], qd * 4 + r);
      const float inv = 1.0f / lr;
      const int q = q0 + w * 32 + i * 16 + qd * 4 + r;
#pragma unroll
      for (int jn = 0; jn < 4; jn++) {
        const int dd = jn * 16 + ln;
        Ob[(size_t)(b * S_ + q) * D + h * HD + dd] = (bf16)(acc_o[i][jn][r] * inv);
      }
    }
}

// final projection: out = O @ Wo + bo; output dtype per flag
__global__ __launch_bounds__(256) void oproj_kernel(const bf16* __restrict__ Ob,
                                                    const bf16* __restrict__ WoT,
                                                    const bf16* __restrict__ bo,
                                                    const int* __restrict__ flag,
                                                    void* __restrict__ outv) {
  __shared__ __align__(16) bf16 As[128 * 64];
  __shared__ __align__(16) bf16 Bs[128 * 64];
  const int isf = *flag;
  const int mt = blockIdx.x, nb = blockIdx.y;
  f32x4 acc[4][4];
  gemm_core(Ob, WoT, mt * 128, nb * 128, As, Bs, acc);
  const int tid = threadIdx.x;
  const int w = tid >> 6, lane = tid & 63;
  const int ln = lane & 15, qd = lane >> 4;
  const int wr = w >> 1, wc = w & 1;
#pragma unroll
  for (int i = 0; i < 4; i++)
#pragma unroll
    for (int j = 0; j < 4; j++) {
      const int col = nb * 128 + wc * 64 + j * 16 + ln;
      const float bb = (float)bo[col];
#pragma unroll
      for (int r = 0; r < 4; r++) {
        const int tok = mt * 128 + wr * 64 + i * 16 + qd * 4 + r;
        const float v = acc[i][j][r] + bb;
        const size_t oi = (size_t)tok * D + col;
        if (isf) ((float*)outv)[oi] = v;
        else ((bf16*)outv)[oi] = (bf16)v;
      }
    }
}

extern "C" void kernel_launch(void* const* d_in, const int* in_sizes, int n_in,
                              void* d_out, int out_size, void* d_ws, size_t ws_size,
                              hipStream_t stream) {
  int* flag = (int*)d_ws;
  bf16* ws = (bf16*)d_ws + 2048;  // 4 KB header

  bf16* WT4 = ws;                       // 4*MAT
  bf16* Xc  = WT4 + 4 * MAT;            // 3*XSZ
  bf16* bc  = Xc + 3 * XSZ;             // 4096
  bf16* Qb  = bc + 4096;                // XSZ each
  bf16* Kb  = Qb + XSZ;
  bf16* VTb = Kb + XSZ;
  bf16* Ob  = VTb + XSZ;
  bf16* Vb  = Ob;  // alias: Vb consumed by transpose_v before attn writes Ob

  detect_k<<<1, 256, 0, stream>>>((const unsigned short*)d_in[3], flag);
  convert_x<<<dim3(2048, 3), 256, 0, stream>>>(d_in[0], d_in[1], d_in[2], flag, Xc);
  convert_bias<<<4, 256, 0, stream>>>(d_in[4], d_in[6], d_in[8], d_in[10], flag, bc);
  transpose4<<<dim3(16, 16, 4), 256, 0, stream>>>(d_in[3], d_in[5], d_in[7], d_in[9], flag, WT4);
  qkv_kernel<<<dim3(32, 24), 256, 0, stream>>>(Xc, WT4, bc, Qb, Kb, Vb);
  transpose_v<<<dim3(32, 32), 256, 0, stream>>>(Vb, VTb);
  attn_kernel<<<dim3(16, 32), 256, 0, stream>>>(Qb, Kb, VTb, Ob);
  oproj_kernel<<<dim3(32, 8), 256, 0, stream>>>(Ob, WT4 + 3 * MAT, bc + 3 * 1024, flag, d_out);
}